// Round 11
// baseline (38.894 us; speedup 1.0000x reference)
//
#include <hip/hip_runtime.h>
#include <math.h>

#define NB 30           // NUM_BINS
#define PS 99           // per-column stride (floats), identical in global table and LDS
#define TPB 256

typedef float f32x4 __attribute__((ext_vector_type(4)));

// precomputed param table: 512 cols x 99 floats (triples cw,ch,dv + sentinel)
__device__ float g_par[512 * PS];

__device__ __forceinline__ float softplus_f(float x) {
    return fmaxf(x, 0.0f) + log1pf(__expf(-fabsf(x)));
}

// softmax -> min-size floor -> cumsum; writes dst[3*k], k=0..NB
__device__ __forceinline__ void stage_cum(const float* __restrict__ u, int v,
                                          float* __restrict__ dst) {
    float e[NB];
#pragma unroll
    for (int k = 0; k < NB; ++k) e[k] = u[v * NB + k];
    float m = e[0];
#pragma unroll
    for (int k = 1; k < NB; ++k) m = fmaxf(m, e[k]);
    float s = 0.f;
#pragma unroll
    for (int k = 0; k < NB; ++k) { e[k] = __expf(e[k] - m); s += e[k]; }
    const float fac = (1.0f - 0.001f * (float)NB) / s;
    float run = 0.f;
    dst[0] = 0.f;
#pragma unroll
    for (int k = 0; k < NB; ++k) {
        run += 0.001f + fac * e[k];
        dst[3 * (k + 1)] = run;
    }
}

__device__ __forceinline__ void col_params(const float* __restrict__ uw,
                                           const float* __restrict__ uh,
                                           const float* __restrict__ ud,
                                           int v, float* __restrict__ pcw) {
    stage_cum(uw, v, pcw);           // cumwidths  -> [3k]
    stage_cum(uh, v, pcw + 1);       // cumheights -> [3k+1]
    pcw[2] = 1.0f;                   // edge derivative == 1 exactly
    pcw[3 * NB + 2] = 1.0f;
#pragma unroll
    for (int k = 1; k < NB; ++k)
        pcw[3 * k + 2] = 0.001f + softplus_f(ud[v * (NB - 1) + k - 1]);
    pcw[93] = 3.0e38f;               // search sentinel
    pcw[94] = 0.f; pcw[95] = 0.f; pcw[96] = 0.f; pcw[97] = 0.f; pcw[98] = 0.f;
}

__global__ void rqs_params_kernel(const float* __restrict__ uw,
                                  const float* __restrict__ uh,
                                  const float* __restrict__ ud, int V) {
    const int v = blockIdx.x * 64 + threadIdx.x;
    if (v < V) col_params(uw, uh, ud, v, &g_par[v * PS]);
}

__device__ __forceinline__ void spline_eval(float cwl, float chl, float d0,
                                            float cwr, float chr, float d1,
                                            float xq, float xraw,
                                            float& o, float& ldv) {
    const float wd = cwr - cwl;
    const float h  = chr - chl;
    const float winv = __builtin_amdgcn_rcpf(wd);
    const float delta = h * winv;
    const float theta = (xq - cwl) * winv;
    const float omt = 1.0f - theta;
    const float t1mt = theta * omt;
    const float th2 = theta * theta;
    const float den = delta + (d0 + d1 - 2.0f * delta) * t1mt;
    const float dinv = __builtin_amdgcn_rcpf(den);
    const float oi = chl + h * (delta * th2 + d0 * t1mt) * dinv;
    const float numd = delta * delta * (d1 * th2 + 2.0f * delta * t1mt + d0 * omt * omt);
    const float li = __logf(numd * dinv * dinv);
    const bool inside = (xraw >= 0.0f) && (xraw <= 1.0f);
    o   = inside ? oi : xraw;        // outside: slope-1 identity (DERIV_OUT==1)
    ldv = inside ? li : 0.0f;
}

// ---- fast path: V==512, B%4096==0. 32-col tiles, 8 blocks/CU, prefetch + NT I/O ----
__global__ __launch_bounds__(TPB, 8) void rqs_main_kernel(
        const float* __restrict__ x_in, float* __restrict__ out,
        float* __restrict__ lad, int B) {
    const int V = 512;
    __shared__ f32x4 pkS4[32 * PS / 4];          // 12.7 KB (792 quads)
    float* pkS = (float*)pkS4;

    const int tid = threadIdx.x;
    const int colTile = blockIdx.x & 15;          // 16 col tiles
    const int rowBlk  = blockIdx.x >> 4;          // 0..127

    // staging = straight linear copy (global layout == LDS layout)
    const f32x4* __restrict__ gp4 = (const f32x4*)&g_par[colTile * 32 * PS];
    for (int i = tid; i < 792; i += TPB) pkS4[i] = gp4[i];
    __syncthreads();

    const int c = tid & 31;
    const int rsub = tid >> 5;                    // 0..7
    const int col = colTile * 32 + c;
    const float* __restrict__ pc = &pkS[c * PS];

    // hoist search levels 1-3 boundaries
    const float c12 = pc[12], c24 = pc[24], c36 = pc[36], c48 = pc[48];
    const float c60 = pc[60], c72 = pc[72], c84 = pc[84];

    int r0 = rowBlk * 32 + rsub * 4;
    float xv[4];
#pragma unroll
    for (int u = 0; u < 4; ++u)
        xv[u] = __builtin_nontemporal_load(&x_in[(size_t)(r0 + u) * V + col]);

    while (true) {
        // ---- prefetch next iteration's x (hides HBM latency under compute) ----
        const int rn = r0 + 4096;
        const bool has = (rn < B);                // wave-uniform
        float xn[4];
        if (has) {
#pragma unroll
            for (int u = 0; u < 4; ++u)
                xn[u] = __builtin_nontemporal_load(&x_in[(size_t)(rn + u) * V + col]);
        }

        float xq[4];
        int jj[4];
#pragma unroll
        for (int u = 0; u < 4; ++u) xq[u] = fminf(fmaxf(xv[u], 0.0f), 1.0f);

        // levels 1-3: register cndmask tree
#pragma unroll
        for (int u = 0; u < 4; ++u) {
            const float xx = xq[u];
            const bool b1 = (c48 <= xx);
            const float l2 = b1 ? c72 : c24;
            const bool b2 = (l2 <= xx);
            const float l3 = b1 ? (b2 ? c84 : c60) : (b2 ? c36 : c12);
            const bool b3 = (l3 <= xx);
            jj[u] = (b1 ? 48 : 0) + (b2 ? 24 : 0) + (b3 ? 12 : 0);
        }
        // levels 4-5: two dependent LDS rounds, 4 chains in flight
#pragma unroll
        for (int u = 0; u < 4; ++u) jj[u] += (pc[jj[u] + 6] <= xq[u]) ? 6 : 0;
#pragma unroll
        for (int u = 0; u < 4; ++u) jj[u] += (pc[jj[u] + 3] <= xq[u]) ? 3 : 0;
#pragma unroll
        for (int u = 0; u < 4; ++u) jj[u] = min(jj[u], 87);

        float cwl[4], chl[4], d0a[4], cwr[4], chr[4], d1a[4];
#pragma unroll
        for (int u = 0; u < 4; ++u) {
            const float* p = pc + jj[u];
            cwl[u] = p[0]; chl[u] = p[1]; d0a[u] = p[2];   // 3x ds_read2_b32
            cwr[u] = p[3]; chr[u] = p[4]; d1a[u] = p[5];
        }

#pragma unroll
        for (int u = 0; u < 4; ++u) {
            float o, ldv;
            spline_eval(cwl[u], chl[u], d0a[u], cwr[u], chr[u], d1a[u],
                        xq[u], xv[u], o, ldv);
            const size_t idx = (size_t)(r0 + u) * V + col;
            __builtin_nontemporal_store(o,   &out[idx]);   // stream writes past L3
            __builtin_nontemporal_store(ldv, &lad[idx]);
        }

        if (!has) break;
        r0 = rn;
#pragma unroll
        for (int u = 0; u < 4; ++u) xv[u] = xn[u];
    }
}

// ---- generic fallback: any V, any B (self-contained, known-good from R3/R7) ----
__global__ __launch_bounds__(TPB, 4) void rqs_gen_kernel(
        const float* __restrict__ x_in, const float* __restrict__ uw,
        const float* __restrict__ uh, const float* __restrict__ ud,
        float* __restrict__ out, float* __restrict__ lad,
        int B, int V, int nct, int rowTiles) {
    __shared__ float pkS[64 * PS];

    const int tid = threadIdx.x;
    const int colTile = blockIdx.x % nct;
    const int rowBlk  = blockIdx.x / nct;
    const int colbase = colTile * 64;

    if (tid < 64 && colbase + tid < V)
        col_params(uw, uh, ud, colbase + tid, &pkS[tid * PS]);
    __syncthreads();

    const int c = tid & 63;
    const int w = tid >> 6;
    const int col = colbase + c;
    if (col >= V) return;
    const float* __restrict__ pc = &pkS[c * PS];

    for (int row = rowBlk * 4 + w; row < B; row += rowTiles * 4) {
        const float xr = x_in[(size_t)row * V + col];
        const float xq = fminf(fmaxf(xr, 0.0f), 1.0f);
        int j = (pc[48] <= xq) ? 48 : 0;
        j += (pc[j + 24] <= xq) ? 24 : 0;
        j += (pc[j + 12] <= xq) ? 12 : 0;
        j += (pc[j +  6] <= xq) ?  6 : 0;
        j += (pc[j +  3] <= xq) ?  3 : 0;
        j = min(j, 87);
        const float* p = pc + j;
        float o, ldv;
        spline_eval(p[0], p[1], p[2], p[3], p[4], p[5], xq, xr, o, ldv);
        out[(size_t)row * V + col] = o;
        lad[(size_t)row * V + col] = ldv;
    }
}

extern "C" void kernel_launch(void* const* d_in, const int* in_sizes, int n_in,
                              void* d_out, int out_size, void* d_ws, size_t ws_size,
                              hipStream_t stream) {
    const float* x  = (const float*)d_in[0];
    const float* uw = (const float*)d_in[1];
    const float* uh = (const float*)d_in[2];
    const float* ud = (const float*)d_in[3];

    const int V = in_sizes[1] / NB;          // 512
    const int B = in_sizes[0] / V;           // 16384

    float* out = (float*)d_out;
    float* lad = out + (size_t)B * V;

    if (V == 512 && (B % 4096) == 0 && B >= 4096) {
        rqs_params_kernel<<<8, 64, 0, stream>>>(uw, uh, ud, V);
        // grid 2048 = 16 col-tiles x 128 rowBlks = 8 blocks/CU, exact passes
        rqs_main_kernel<<<2048, TPB, 0, stream>>>(x, out, lad, B);
    } else {
        const int nct = (V + 63) / 64;
        int rowTiles = (B + 3) / 4;
        if (rowTiles > 128) rowTiles = 128;
        rqs_gen_kernel<<<nct * rowTiles, TPB, 0, stream>>>(
            x, uw, uh, ud, out, lad, B, V, nct, rowTiles);
    }
}

// Round 12
// 32.539 us; speedup vs baseline: 1.1953x; 1.1953x over previous
//
#include <hip/hip_runtime.h>
#include <math.h>

#define NB 30           // NUM_BINS
#define PS 99           // per-column stride (floats), identical in global table and LDS
#define TPB 256

typedef float f32x4 __attribute__((ext_vector_type(4)));

// precomputed param table: 512 cols x 99 floats (triples cw,ch,dv + sentinel)
__device__ float g_par[512 * PS];

__device__ __forceinline__ float softplus_f(float x) {
    return fmaxf(x, 0.0f) + log1pf(__expf(-fabsf(x)));
}

// softmax -> min-size floor -> cumsum; writes dst[3*k], k=0..NB
__device__ __forceinline__ void stage_cum(const float* __restrict__ u, int v,
                                          float* __restrict__ dst) {
    float e[NB];
#pragma unroll
    for (int k = 0; k < NB; ++k) e[k] = u[v * NB + k];
    float m = e[0];
#pragma unroll
    for (int k = 1; k < NB; ++k) m = fmaxf(m, e[k]);
    float s = 0.f;
#pragma unroll
    for (int k = 0; k < NB; ++k) { e[k] = __expf(e[k] - m); s += e[k]; }
    const float fac = (1.0f - 0.001f * (float)NB) / s;
    float run = 0.f;
    dst[0] = 0.f;
#pragma unroll
    for (int k = 0; k < NB; ++k) {
        run += 0.001f + fac * e[k];
        dst[3 * (k + 1)] = run;
    }
}

__device__ __forceinline__ void col_params(const float* __restrict__ uw,
                                           const float* __restrict__ uh,
                                           const float* __restrict__ ud,
                                           int v, float* __restrict__ pcw) {
    stage_cum(uw, v, pcw);           // cumwidths  -> [3k]
    stage_cum(uh, v, pcw + 1);       // cumheights -> [3k+1]
    pcw[2] = 1.0f;                   // edge derivative == 1 exactly
    pcw[3 * NB + 2] = 1.0f;
#pragma unroll
    for (int k = 1; k < NB; ++k)
        pcw[3 * k + 2] = 0.001f + softplus_f(ud[v * (NB - 1) + k - 1]);
    pcw[93] = 3.0e38f;               // search sentinel
    pcw[94] = 0.f; pcw[95] = 0.f; pcw[96] = 0.f; pcw[97] = 0.f; pcw[98] = 0.f;
}

__global__ void rqs_params_kernel(const float* __restrict__ uw,
                                  const float* __restrict__ uh,
                                  const float* __restrict__ ud, int V) {
    const int v = blockIdx.x * 64 + threadIdx.x;
    if (v < V) col_params(uw, uh, ud, v, &g_par[v * PS]);
}

__device__ __forceinline__ void spline_eval(float cwl, float chl, float d0,
                                            float cwr, float chr, float d1,
                                            float xq, float xraw,
                                            float& o, float& ldv) {
    const float wd = cwr - cwl;
    const float h  = chr - chl;
    const float winv = __builtin_amdgcn_rcpf(wd);
    const float delta = h * winv;
    const float theta = (xq - cwl) * winv;
    const float omt = 1.0f - theta;
    const float t1mt = theta * omt;
    const float th2 = theta * theta;
    const float den = delta + (d0 + d1 - 2.0f * delta) * t1mt;
    const float dinv = __builtin_amdgcn_rcpf(den);
    const float oi = chl + h * (delta * th2 + d0 * t1mt) * dinv;
    const float numd = delta * delta * (d1 * th2 + 2.0f * delta * t1mt + d0 * omt * omt);
    const float li = __logf(numd * dinv * dinv);
    const bool inside = (xraw >= 0.0f) && (xraw <= 1.0f);
    o   = inside ? oi : xraw;        // outside: slope-1 identity (DERIV_OUT==1)
    ldv = inside ? li : 0.0f;
}

// ---- fast path: V==512, B%4096==0. 32-col tiles, 8 blocks/CU, prefetch + NT stores ----
__global__ __launch_bounds__(TPB, 8) void rqs_main_kernel(
        const float* __restrict__ x_in, float* __restrict__ out,
        float* __restrict__ lad, int B) {
    const int V = 512;
    __shared__ f32x4 pkS4[32 * PS / 4];          // 12.7 KB (792 quads)
    float* pkS = (float*)pkS4;

    const int tid = threadIdx.x;
    const int colTile = blockIdx.x & 15;          // 16 col tiles
    const int rowBlk  = blockIdx.x >> 4;          // 0..127

    // staging = straight linear copy (global layout == LDS layout)
    const f32x4* __restrict__ gp4 = (const f32x4*)&g_par[colTile * 32 * PS];
    for (int i = tid; i < 792; i += TPB) pkS4[i] = gp4[i];
    __syncthreads();

    const int c = tid & 31;
    const int rsub = tid >> 5;                    // 0..7
    const int col = colTile * 32 + c;
    const float* __restrict__ pc = &pkS[c * PS];

    // hoist search levels 1-3 boundaries
    const float c12 = pc[12], c24 = pc[24], c36 = pc[36], c48 = pc[48];
    const float c60 = pc[60], c72 = pc[72], c84 = pc[84];

    int r0 = rowBlk * 32 + rsub * 4;
    float xv[4];
#pragma unroll
    for (int u = 0; u < 4; ++u) xv[u] = x_in[(size_t)(r0 + u) * V + col];

    while (true) {
        // ---- prefetch next iteration's x (hides HBM latency under compute) ----
        const int rn = r0 + 4096;
        const bool has = (rn < B);                // wave-uniform
        float xn[4];
        if (has) {
#pragma unroll
            for (int u = 0; u < 4; ++u) xn[u] = x_in[(size_t)(rn + u) * V + col];
        }

        float xq[4];
        int jj[4];
#pragma unroll
        for (int u = 0; u < 4; ++u) xq[u] = fminf(fmaxf(xv[u], 0.0f), 1.0f);

        // levels 1-3: register cndmask tree
#pragma unroll
        for (int u = 0; u < 4; ++u) {
            const float xx = xq[u];
            const bool b1 = (c48 <= xx);
            const float l2 = b1 ? c72 : c24;
            const bool b2 = (l2 <= xx);
            const float l3 = b1 ? (b2 ? c84 : c60) : (b2 ? c36 : c12);
            const bool b3 = (l3 <= xx);
            jj[u] = (b1 ? 48 : 0) + (b2 ? 24 : 0) + (b3 ? 12 : 0);
        }
        // levels 4-5: two dependent LDS rounds, 4 chains in flight
#pragma unroll
        for (int u = 0; u < 4; ++u) jj[u] += (pc[jj[u] + 6] <= xq[u]) ? 6 : 0;
#pragma unroll
        for (int u = 0; u < 4; ++u) jj[u] += (pc[jj[u] + 3] <= xq[u]) ? 3 : 0;
#pragma unroll
        for (int u = 0; u < 4; ++u) jj[u] = min(jj[u], 87);

        float cwl[4], chl[4], d0a[4], cwr[4], chr[4], d1a[4];
#pragma unroll
        for (int u = 0; u < 4; ++u) {
            const float* p = pc + jj[u];
            cwl[u] = p[0]; chl[u] = p[1]; d0a[u] = p[2];   // 3x ds_read2_b32
            cwr[u] = p[3]; chr[u] = p[4]; d1a[u] = p[5];
        }

#pragma unroll
        for (int u = 0; u < 4; ++u) {
            float o, ldv;
            spline_eval(cwl[u], chl[u], d0a[u], cwr[u], chr[u], d1a[u],
                        xq[u], xv[u], o, ldv);
            const size_t idx = (size_t)(r0 + u) * V + col;
            __builtin_nontemporal_store(o,   &out[idx]);   // stream writes past L3
            __builtin_nontemporal_store(ldv, &lad[idx]);
        }

        if (!has) break;
        r0 = rn;
#pragma unroll
        for (int u = 0; u < 4; ++u) xv[u] = xn[u];
    }
}

// ---- generic fallback: any V, any B (self-contained, known-good from R3/R7) ----
__global__ __launch_bounds__(TPB, 4) void rqs_gen_kernel(
        const float* __restrict__ x_in, const float* __restrict__ uw,
        const float* __restrict__ uh, const float* __restrict__ ud,
        float* __restrict__ out, float* __restrict__ lad,
        int B, int V, int nct, int rowTiles) {
    __shared__ float pkS[64 * PS];

    const int tid = threadIdx.x;
    const int colTile = blockIdx.x % nct;
    const int rowBlk  = blockIdx.x / nct;
    const int colbase = colTile * 64;

    if (tid < 64 && colbase + tid < V)
        col_params(uw, uh, ud, colbase + tid, &pkS[tid * PS]);
    __syncthreads();

    const int c = tid & 63;
    const int w = tid >> 6;
    const int col = colbase + c;
    if (col >= V) return;
    const float* __restrict__ pc = &pkS[c * PS];

    for (int row = rowBlk * 4 + w; row < B; row += rowTiles * 4) {
        const float xr = x_in[(size_t)row * V + col];
        const float xq = fminf(fmaxf(xr, 0.0f), 1.0f);
        int j = (pc[48] <= xq) ? 48 : 0;
        j += (pc[j + 24] <= xq) ? 24 : 0;
        j += (pc[j + 12] <= xq) ? 12 : 0;
        j += (pc[j +  6] <= xq) ?  6 : 0;
        j += (pc[j +  3] <= xq) ?  3 : 0;
        j = min(j, 87);
        const float* p = pc + j;
        float o, ldv;
        spline_eval(p[0], p[1], p[2], p[3], p[4], p[5], xq, xr, o, ldv);
        out[(size_t)row * V + col] = o;
        lad[(size_t)row * V + col] = ldv;
    }
}

extern "C" void kernel_launch(void* const* d_in, const int* in_sizes, int n_in,
                              void* d_out, int out_size, void* d_ws, size_t ws_size,
                              hipStream_t stream) {
    const float* x  = (const float*)d_in[0];
    const float* uw = (const float*)d_in[1];
    const float* uh = (const float*)d_in[2];
    const float* ud = (const float*)d_in[3];

    const int V = in_sizes[1] / NB;          // 512
    const int B = in_sizes[0] / V;           // 16384

    float* out = (float*)d_out;
    float* lad = out + (size_t)B * V;

    if (V == 512 && (B % 4096) == 0 && B >= 4096) {
        rqs_params_kernel<<<8, 64, 0, stream>>>(uw, uh, ud, V);
        // grid 2048 = 16 col-tiles x 128 rowBlks = 8 blocks/CU, exact passes
        rqs_main_kernel<<<2048, TPB, 0, stream>>>(x, out, lad, B);
    } else {
        const int nct = (V + 63) / 64;
        int rowTiles = (B + 3) / 4;
        if (rowTiles > 128) rowTiles = 128;
        rqs_gen_kernel<<<nct * rowTiles, TPB, 0, stream>>>(
            x, uw, uh, ud, out, lad, B, V, nct, rowTiles);
    }
}